// Round 14
// baseline (157.560 us; speedup 1.0000x reference)
//
#include <hip/hip_runtime.h>
#include <stdint.h>

#define DEVI __device__ __forceinline__

typedef unsigned short u16;
typedef __attribute__((ext_vector_type(4))) float f32x4;
typedef __attribute__((ext_vector_type(16))) float f32x16;
typedef __attribute__((ext_vector_type(8))) short bf16x8;
typedef __attribute__((ext_vector_type(2))) unsigned int u32x2;

constexpr int T_LEN = 2048;
constexpr int BSZ   = 2;
constexpr int DM    = 1024;
constexpr int NH    = 16;
constexpr int HD    = 64;
constexpr int MROWS = T_LEN * BSZ;   // 4096
constexpr float LORA_S = 16.0f / 16.0f;  // SCALE / RANK
// Q pre-scale: 1/sqrt(64) * log2(e)  -> scores land in exp2 domain
constexpr float QSCALE = 0.125f * 1.4426950408889634f;

DEVI u16 f2bf(float x) {
  union { float f; uint32_t u; } v; v.f = x;
  uint32_t r = (v.u + 0x7FFFu + ((v.u >> 16) & 1u)) >> 16;  // RNE
  return (u16)r;
}

DEVI uint32_t pk2bf(float a, float b) {  // low = a, high = b (RNE)
  return (uint32_t)f2bf(a) | ((uint32_t)f2bf(b) << 16);
}

// exp2, raw bits (bf16 truncation via byte-perm; bias cancels in P/l ratio)
DEVI uint32_t e2r(float x) {
  union { float f; uint32_t u; } v;
  v.f = __builtin_amdgcn_exp2f(x);
  return v.u;
}

DEVI void gload_lds16(const void* g, void* l) {
  __builtin_amdgcn_global_load_lds(
      (const __attribute__((address_space(1))) void*)g,
      (__attribute__((address_space(3))) void*)l, 16, 0, 0);
}

DEVI f32x4 mfma16(bf16x8 a, bf16x8 b, f32x4 c) {
  return __builtin_amdgcn_mfma_f32_16x16x32_bf16(a, b, c, 0, 0, 0);
}
DEVI f32x16 mfma32(bf16x8 a, bf16x8 b, f32x16 c) {
  return __builtin_amdgcn_mfma_f32_32x32x16_bf16(a, b, c, 0, 0, 0);
}

// attn K/V tiles: 32 rows x 256B (16 slots); logical slot l, row rc.
DEVI int kvswz(int rc, int l) { return rc * 128 + ((l ^ (rc & 15)) << 3); }

// counted-vmcnt barrier (T4): loads stay in flight across the barrier
#define WAITBAR(N)                                        \
  do {                                                    \
    asm volatile("s_waitcnt vmcnt(" #N ")" ::: "memory"); \
    __builtin_amdgcn_sched_barrier(0);                    \
    __builtin_amdgcn_s_barrier();                         \
    __builtin_amdgcn_sched_barrier(0);                    \
  } while (0)

// plain barrier (sched-fenced)
#define BARO()                                            \
  do {                                                    \
    __builtin_amdgcn_sched_barrier(0);                    \
    __builtin_amdgcn_s_barrier();                         \
    __builtin_amdgcn_sched_barrier(0);                    \
  } while (0)

// ---------------- prep: fold LoRA into Wk/Wv, cast weights + query to bf16 --
__global__ void prep_kernel(const float* __restrict__ query,
                            const float* __restrict__ W,
                            const float* __restrict__ ka, const float* __restrict__ kb,
                            const float* __restrict__ va, const float* __restrict__ vb,
                            const float* __restrict__ ow,
                            u16* __restrict__ Wm, u16* __restrict__ Wo,
                            u16* __restrict__ Aq) {
  const int W3 = 3 * DM * DM;
  const int WO = DM * DM;
  const int AQ = MROWS * DM;
  const int total = W3 + WO + AQ;
  for (int idx = blockIdx.x * blockDim.x + threadIdx.x; idx < total;
       idx += gridDim.x * blockDim.x) {
    if (idx < W3) {
      const int n = idx >> 10, k = idx & 1023;
      float w = W[idx];
      if (n >= 2 * DM) {
        const int n2 = n - 2 * DM;
        float a = 0.f;
#pragma unroll
        for (int r = 0; r < 16; ++r) a += va[r * DM + k] * vb[r * DM + n2];
        w += LORA_S * a;
      } else if (n >= DM) {
        const int n2 = n - DM;
        float a = 0.f;
#pragma unroll
        for (int r = 0; r < 16; ++r) a += ka[r * DM + k] * kb[r * DM + n2];
        w += LORA_S * a;
      }
      Wm[idx] = f2bf(w);
    } else if (idx < W3 + WO) {
      const int i = idx - W3;
      Wo[i] = f2bf(ow[i]);
    } else {
      const int i = idx - W3 - WO;
      Aq[i] = f2bf(query[i]);
    }
  }
}

// ---------------- GEMM: C[m][n] = sum_k A[m][k]*Bt[n][k] + bias[n] ----------
// BK=32, 2-buffer LDS (32 KB -> 4 blocks/CU, 16 waves/CU), counted vmcnt(4).
template <int EPIL>
__global__ __launch_bounds__(256, 4) void gemm_bt(
    const u16* __restrict__ A, const u16* __restrict__ Bt,
    const float* __restrict__ bias, float* __restrict__ Cf,
    u16* __restrict__ Qb, u16* __restrict__ Kb, u16* __restrict__ Vt,
    int M, int N, int K) {
  constexpr int BM = 128, BN = 128, BK = 32;
  __shared__ alignas(16) u16 SM[2][2][4096];  // 32 KB: [buf][A/B][64x64 u16]
  const int tid = threadIdx.x;
  const int wv = tid >> 6, ln = tid & 63;
  const int l16 = ln & 15, lhi = ln >> 4;

  // XCD 2-D super-tile decode (bijective): 4 row-quarters x 2 col-halves
  const int bid = blockIdx.x;
  const int half = (N >> 7) >> 1;     // col-blocks per half (12 or 4)
  const int x = bid & 7, j = bid >> 3;
  const int rq = x >> 1, ch = x & 1;
  const int jc = j % half, jr = j / half;  // col fastest within XCD
  const int row0 = (rq * 8 + jr) * BM;     // M/128 = 32 rows -> 8 per quarter
  const int col0 = (ch * half + jc) * BN;
  const int wr = (wv >> 1) * 64, wc = (wv & 1) * 64;

  f32x4 acc[4][4];
#pragma unroll
  for (int i = 0; i < 4; ++i)
#pragma unroll
    for (int j2 = 0; j2 < 4; ++j2) acc[i][j2] = f32x4{0.f, 0.f, 0.f, 0.f};

  const int lrA = wv * 16 + (ln >> 3);   // j=0 ldsrow
  const int lrB = lrA + 8;               // j=1 ldsrow
  const int s_ = ln & 7;
  const int la = s_ ^ (lrA & 7), lb = s_ ^ (lrB & 7);
  const int ra = lrA + 64 * (la >> 2), ca = (la & 3) * 8;
  const int rb = lrB + 64 * (lb >> 2), cb = (lb & 3) * 8;

  const u16* pa0 = A + (size_t)(row0 + ra) * K + ca;
  const u16* pa1 = A + (size_t)(row0 + rb) * K + cb;
  const u16* pb0 = Bt + (size_t)(col0 + ra) * K + ca;
  const u16* pb1 = Bt + (size_t)(col0 + rb) * K + cb;

  auto stagep = [&](int buf) {
    gload_lds16(pa0, &SM[buf][0][(wv * 16) * 64]);
    gload_lds16(pa1, &SM[buf][0][(wv * 16 + 8) * 64]);
    gload_lds16(pb0, &SM[buf][1][(wv * 16) * 64]);
    gload_lds16(pb1, &SM[buf][1][(wv * 16 + 8) * 64]);
    pa0 += BK; pa1 += BK; pb0 += BK; pb1 += BK;
  };

  auto compute = [&](int buf) {
    const u16* Al = SM[buf][0];
    const u16* Bl = SM[buf][1];
    bf16x8 af[4], bfr[4];
#pragma unroll
    for (int m = 0; m < 4; ++m) {
      const int r = wr + m * 16 + l16, lr = r & 63;
      const int sl = (lhi | ((r >> 6) << 2)) ^ (lr & 7);
      af[m] = *(const bf16x8*)&Al[lr * 64 + sl * 8];
    }
#pragma unroll
    for (int n = 0; n < 4; ++n) {
      const int r = wc + n * 16 + l16, lr = r & 63;
      const int sl = (lhi | ((r >> 6) << 2)) ^ (lr & 7);
      bfr[n] = *(const bf16x8*)&Bl[lr * 64 + sl * 8];
    }
#pragma unroll
    for (int m = 0; m < 4; ++m)
#pragma unroll
      for (int n = 0; n < 4; ++n) acc[m][n] = mfma16(af[m], bfr[n], acc[m][n]);
  };

  const int NS = K / BK;  // 32 for K=1024 (even)
  stagep(0); stagep(1);   // 8 loads/wave in flight

  for (int t = 0; t < NS - 2; t += 2) {
    WAITBAR(4); compute(0); BARO(); stagep(0);
    WAITBAR(4); compute(1); BARO(); stagep(1);
  }
  WAITBAR(4); compute(0);   // t = NS-2 (stage NS-1 still in flight)
  WAITBAR(0); compute(1);   // t = NS-1

  if constexpr (EPIL == 0) {
    if (col0 >= 2 * DM) {
      // ---- V block: transpose 128x128 tile through LDS, coalesced stores
      u16* Cl = (u16*)SM;  // 32 KB; all buffers dead past this barrier
      __syncthreads();
#pragma unroll
      for (int m = 0; m < 4; ++m)
#pragma unroll
        for (int n = 0; n < 4; ++n) {
          const int lc = wc + n * 16 + l16;
          const float bc = bias[col0 + lc];
#pragma unroll
          for (int r = 0; r < 4; ++r) {
            const int rl = wr + m * 16 + lhi * 4 + r;
            const int tl = rl >> 1, bb = rl & 1;
            Cl[lc * 128 + bb * 64 + (((tl >> 3) ^ (lc & 7)) << 3) + (tl & 7)] =
                f2bf(acc[m][n][r] + bc);
          }
        }
      __syncthreads();
      const int h0 = (col0 - 2 * DM) >> 6;
      const int t0 = row0 >> 1;
#pragma unroll
      for (int i = 0; i < 8; ++i) {
        const int cid = i * 256 + tid;  // 2048 chunks of 8 u16
        const int lc = cid >> 4, bb = (cid >> 3) & 1, tc = cid & 7;
        bf16x8 ch2 = *(const bf16x8*)&Cl[lc * 128 + bb * 64 + ((tc ^ (lc & 7)) << 3)];
        const int h = h0 + (lc >> 6), dd = lc & 63;
        *(bf16x8*)&Vt[(((size_t)(bb * NH + h)) * HD + dd) * T_LEN + t0 + tc * 8] = ch2;
      }
      return;
    }
  }

#pragma unroll
  for (int m = 0; m < 4; ++m) {
#pragma unroll
    for (int n = 0; n < 4; ++n) {
      const int col = col0 + wc + n * 16 + l16;
      const float bc = bias[col];
#pragma unroll
      for (int r = 0; r < 4; ++r) {
        const int row = row0 + wr + m * 16 + lhi * 4 + r;
        const float v = acc[m][n][r] + bc;
        if constexpr (EPIL == 0) {
          const int t = row >> 1, b = row & 1;  // row = t*BSZ + b
          if (col < DM) {
            const int h = col >> 6, dd = col & 63;
            Qb[(((size_t)(b * NH + h)) * T_LEN + t) * HD + dd] = f2bf(v * QSCALE);
          } else {
            const int c2 = col - DM, h = c2 >> 6, dd = c2 & 63;
            Kb[(((size_t)(b * NH + h)) * T_LEN + t) * HD + dd] = f2bf(v);
          }
        } else {
          Cf[(size_t)row * N + col] = v;
        }
      }
    }
  }
}

// ---------------- flash attention, split-KV halves --------------------------
// 1024 blocks (4/CU, 4 waves/SIMD): block = (head, kv-half, q-chunk). 16 KV
// tiles per block in a 2-buffer 32KB rotation with counted vmcnt(4) (T4).
// Max-free softmax -> partials are unnormalized sums: Opart = sum PV (f32),
// Lpart = sum P; merge kernel adds halves and normalizes. T5 setprio on MFMA.
__global__ __launch_bounds__(256, 4) void attn_kernel(
    const u16* __restrict__ Qb, const u16* __restrict__ Kb,
    const u16* __restrict__ Vt, float* __restrict__ Opart,
    float* __restrict__ Lpart) {
  constexpr int KBLK = 64;
  __shared__ alignas(16) u16 KV[2][2][32 * 128];  // 32 KB: [buf][K/V][packed tile]

  const int tid = threadIdx.x;
  const int wv = tid >> 6, ln = tid & 63;
  const int l32 = ln & 31, hi = ln >> 5;

  // XCD-aware decode: XCD x owns heads 4x..4x+3 (all halves + q-chunks)
  const int bid = blockIdx.x;
  const int lb = (bid & 7) * 128 + (bid >> 3);
  const int bh = lb >> 5;                 // head index 0..31
  const int rem = lb & 31;
  const int kvh = rem >> 4;               // kv half 0/1
  const int q0 = (rem & 15) * 128 + wv * 32;

  const u16* Qh = Qb + (size_t)bh * T_LEN * HD;
  const u16* Kh = Kb + (size_t)bh * T_LEN * HD;
  const u16* Vh = Vt + (size_t)bh * HD * T_LEN;

  // Q B-fragments: row = q = l32, k = kd*16 + hi*8 + j  (pre-scaled by QSCALE)
  bf16x8 qf[4];
#pragma unroll
  for (int kd = 0; kd < 4; ++kd)
    qf[kd] = *(const bf16x8*)&Qh[(size_t)(q0 + l32) * HD + kd * 16 + hi * 8];

  bf16x8 ones;
#pragma unroll
  for (int i = 0; i < 8; ++i) ones[i] = (short)0x3F80;  // bf16 1.0

  f32x16 ot[2] = {f32x16{}, f32x16{}};  // O^T accumulators (dim tiles 0,1)
  f32x16 lacc = f32x16{};               // row-sum accumulator (all rows = li)

  // staging lane map (inverse swizzle), hoisted once; running global pointers
  const int g_row = ln >> 4;            // 0..3 within instr
  const int g_s   = ln & 15;
  const int j0 = wv * 2, j1 = wv * 2 + 1;
  const int row0r = 4 * j0 + g_row, row1r = 4 * j1 + g_row;
  const int l0 = g_s ^ (row0r & 15), l1 = g_s ^ (row1r & 15);
  const int lr0 = row0r + 32 * (l0 >> 3), lr1 = row1r + 32 * (l1 >> 3);
  const int c80 = (l0 & 7) * 8, c81 = (l1 & 7) * 8;

  const int kt0 = kvh * (T_LEN / 2);    // this block's key range base
  const u16* ks0 = Kh + (size_t)(kt0 + lr0) * HD + c80;
  const u16* ks1 = Kh + (size_t)(kt0 + lr1) * HD + c81;
  const u16* vs0 = Vh + (size_t)lr0 * T_LEN + kt0 + c80;
  const u16* vs1 = Vh + (size_t)lr1 * T_LEN + kt0 + c81;

  auto stagep = [&](int buf) {
    gload_lds16(ks0, &KV[buf][0][j0 * 512]);
    gload_lds16(ks1, &KV[buf][0][j1 * 512]);
    gload_lds16(vs0, &KV[buf][1][j0 * 512]);
    gload_lds16(vs1, &KV[buf][1][j1 * 512]);
    ks0 += KBLK * HD; ks1 += KBLK * HD; vs0 += KBLK; vs1 += KBLK;
  };

  auto compute = [&](int buf) {
    const u16* Kl = KV[buf][0];
    const u16* Vl = KV[buf][1];
    f32x16 st[2] = {f32x16{}, f32x16{}};
    __builtin_amdgcn_s_setprio(1);
#pragma unroll
    for (int kd = 0; kd < 4; ++kd) {
      bf16x8 k0 = *(const bf16x8*)&Kl[kvswz(l32, kd * 2 + hi)];
      bf16x8 k1 = *(const bf16x8*)&Kl[kvswz(l32, 8 + kd * 2 + hi)];
      st[0] = mfma32(k0, qf[kd], st[0]);
      st[1] = mfma32(k1, qf[kd], st[1]);
    }
    __builtin_amdgcn_s_setprio(0);
    // P = exp2(S^T) packed to bf16 pairs (truncation; bias cancels in P/l)
    uint32_t c[2][8];
#pragma unroll
    for (int mk = 0; mk < 2; ++mk)
#pragma unroll
      for (int d = 0; d < 8; ++d)
        c[mk][d] = __builtin_amdgcn_perm(e2r(st[mk][2 * d + 1]),
                                         e2r(st[mk][2 * d]), 0x07060302u);
    __builtin_amdgcn_s_setprio(1);
#pragma unroll
    for (int ksl = 0; ksl < 4; ++ksl) {
      const int mk = ksl >> 1, s2 = ksl & 1;
      uint32_t a0 = c[mk][4 * s2 + 0], b0 = c[mk][4 * s2 + 2];
      uint32_t a1 = c[mk][4 * s2 + 1], b1 = c[mk][4 * s2 + 3];
      u32x2 r0 = __builtin_amdgcn_permlane32_swap(a0, b0, false, false);
      u32x2 r1 = __builtin_amdgcn_permlane32_swap(a1, b1, false, false);
      union { bf16x8 v; uint32_t u[4]; } pu;
      pu.u[0] = r0[0]; pu.u[1] = r1[0]; pu.u[2] = r0[1]; pu.u[3] = r1[1];
      bf16x8 vf0 = *(const bf16x8*)&Vl[kvswz(l32, ksl * 2 + hi)];
      bf16x8 vf1 = *(const bf16x8*)&Vl[kvswz(l32, 8 + ksl * 2 + hi)];
      ot[0] = mfma32(vf0, pu.v, ot[0]);
      ot[1] = mfma32(vf1, pu.v, ot[1]);
      lacc = mfma32(ones, pu.v, lacc);
    }
    __builtin_amdgcn_s_setprio(0);
  };

  // 16 tiles, 2-buffer rotation (gemm-proven): 2 stages (8 loads) in flight
  stagep(0); stagep(1);
  for (int it = 0; it < 7; ++it) {
    WAITBAR(4); compute(0); BARO(); stagep(0);
    WAITBAR(4); compute(1); BARO(); stagep(1);
  }
  WAITBAR(4); compute(0);
  WAITBAR(0); compute(1);

  // partial epilogue: f32 O^T quads + L to workspace (merged later)
  const int q = q0 + l32;
  const size_t obase = ((size_t)(kvh * 32 + bh) * T_LEN + q) * HD;
#pragma unroll
  for (int dt = 0; dt < 2; ++dt) {
#pragma unroll
    for (int g = 0; g < 4; ++g) {
      f32x4 w;
      w[0] = ot[dt][4 * g + 0]; w[1] = ot[dt][4 * g + 1];
      w[2] = ot[dt][4 * g + 2]; w[3] = ot[dt][4 * g + 3];
      *(f32x4*)&Opart[obase + dt * 32 + 8 * g + 4 * hi] = w;
    }
  }
  if (hi == 0) Lpart[(size_t)(kvh * 32 + bh) * T_LEN + q] = lacc[0];
}

// ---------------- merge: O = (O0+O1)/(L0+L1), f32 -> bf16 Ob ----------------
__global__ __launch_bounds__(256) void merge_kernel(
    const float* __restrict__ Op, const float* __restrict__ Lp,
    u16* __restrict__ Ob) {
  constexpr int HALF_O = 32 * T_LEN * HD;   // elements per half
  constexpr int HALF_L = 32 * T_LEN;
  const int total = HALF_O / 4;             // f32x4 quads
  for (int i = blockIdx.x * blockDim.x + threadIdx.x; i < total;
       i += gridDim.x * blockDim.x) {
    const int d4 = (i & 15) * 4;            // dim 0..60
    const int q  = (i >> 4) & (T_LEN - 1);
    const int bh = i >> 15;                 // 0..31
    const size_t base = ((size_t)bh * T_LEN + q) * HD + d4;
    f32x4 a = *(const f32x4*)&Op[base];
    f32x4 c = *(const f32x4*)&Op[base + HALF_O];
    const float inv = 1.0f / (Lp[bh * T_LEN + q] + Lp[bh * T_LEN + q + HALF_L]);
    u32x2 w;
    w[0] = pk2bf((a[0] + c[0]) * inv, (a[1] + c[1]) * inv);
    w[1] = pk2bf((a[2] + c[2]) * inv, (a[3] + c[3]) * inv);
    const int b = bh >> 4, h = bh & 15;
    *(u32x2*)&Ob[((size_t)q * BSZ + b) * DM + h * HD + d4] = w;
  }
}

// ---------------- launcher --------------------------------------------------
extern "C" void kernel_launch(void* const* d_in, const int* in_sizes, int n_in,
                              void* d_out, int out_size, void* d_ws, size_t ws_size,
                              hipStream_t stream) {
  const float* query = (const float*)d_in[0];
  const float* W     = (const float*)d_in[5];
  const float* bias  = (const float*)d_in[6];
  const float* ow    = (const float*)d_in[7];
  const float* ob    = (const float*)d_in[8];
  const float* ka    = (const float*)d_in[9];
  const float* kb    = (const float*)d_in[10];
  const float* va    = (const float*)d_in[11];
  const float* vb    = (const float*)d_in[12];

  char* ws = (char*)d_ws;
  u16* Wm = (u16*)ws; ws += (size_t)3 * DM * DM * 2;       // 6 MB
  u16* Wo = (u16*)ws; ws += (size_t)DM * DM * 2;           // 2 MB
  u16* Aq = (u16*)ws; ws += (size_t)MROWS * DM * 2;        // 8 MB
  u16* Qb = (u16*)ws; ws += (size_t)BSZ * NH * T_LEN * HD * 2;  // 8 MB
  u16* Kb = (u16*)ws; ws += (size_t)BSZ * NH * T_LEN * HD * 2;  // 8 MB
  u16* Vt = (u16*)ws; ws += (size_t)BSZ * NH * T_LEN * HD * 2;  // 8 MB
  u16* Ob = (u16*)ws; ws += (size_t)MROWS * DM * 2;        // 8 MB
  float* Opart = (float*)ws; ws += (size_t)2 * 32 * T_LEN * HD * 4;  // 33.5 MB
  float* Lpart = (float*)ws; ws += (size_t)2 * 32 * T_LEN * 4;       // 0.5 MB

  prep_kernel<<<2048, 256, 0, stream>>>(query, W, ka, kb, va, vb, ow, Wm, Wo, Aq);

  gemm_bt<0><<<(MROWS / 128) * ((3 * DM) / 128), 256, 0, stream>>>(
      Aq, Wm, bias, nullptr, Qb, Kb, Vt, MROWS, 3 * DM, DM);

  attn_kernel<<<1024, 256, 0, stream>>>(Qb, Kb, Vt, Opart, Lpart);

  merge_kernel<<<2048, 256, 0, stream>>>(Opart, Lpart, Ob);

  gemm_bt<1><<<(MROWS / 128) * (DM / 128), 256, 0, stream>>>(
      Ob, Wo, ob, (float*)d_out, nullptr, nullptr, nullptr, MROWS, DM, DM);
}

// Round 15
// 109.732 us; speedup vs baseline: 1.4359x; 1.4359x over previous
//
#include <hip/hip_runtime.h>
#include <stdint.h>

#define DEVI __device__ __forceinline__

typedef unsigned short u16;
typedef __attribute__((ext_vector_type(4))) float f32x4;
typedef __attribute__((ext_vector_type(16))) float f32x16;
typedef __attribute__((ext_vector_type(8))) short bf16x8;
typedef __attribute__((ext_vector_type(2))) unsigned int u32x2;

constexpr int T_LEN = 2048;
constexpr int BSZ   = 2;
constexpr int DM    = 1024;
constexpr int NH    = 16;
constexpr int HD    = 64;
constexpr int MROWS = T_LEN * BSZ;   // 4096
constexpr float LORA_S = 16.0f / 16.0f;  // SCALE / RANK
// Q pre-scale: 1/sqrt(64) * log2(e)  -> scores land in exp2 domain
constexpr float QSCALE = 0.125f * 1.4426950408889634f;

DEVI u16 f2bf(float x) {
  union { float f; uint32_t u; } v; v.f = x;
  uint32_t r = (v.u + 0x7FFFu + ((v.u >> 16) & 1u)) >> 16;  // RNE
  return (u16)r;
}

DEVI uint32_t pk2bf(float a, float b) {  // low = a, high = b (RNE)
  return (uint32_t)f2bf(a) | ((uint32_t)f2bf(b) << 16);
}

// exp2, raw bits (bf16 truncation via byte-perm; bias cancels in P/l ratio)
DEVI uint32_t e2r(float x) {
  union { float f; uint32_t u; } v;
  v.f = __builtin_amdgcn_exp2f(x);
  return v.u;
}

DEVI void gload_lds16(const void* g, void* l) {
  __builtin_amdgcn_global_load_lds(
      (const __attribute__((address_space(1))) void*)g,
      (__attribute__((address_space(3))) void*)l, 16, 0, 0);
}

DEVI f32x4 mfma16(bf16x8 a, bf16x8 b, f32x4 c) {
  return __builtin_amdgcn_mfma_f32_16x16x32_bf16(a, b, c, 0, 0, 0);
}
DEVI f32x16 mfma32(bf16x8 a, bf16x8 b, f32x16 c) {
  return __builtin_amdgcn_mfma_f32_32x32x16_bf16(a, b, c, 0, 0, 0);
}

// attn K/V tiles: 32 rows x 256B (16 slots); logical slot l, row rc.
DEVI int kvswz(int rc, int l) { return rc * 128 + ((l ^ (rc & 15)) << 3); }

// counted-vmcnt barrier (T4): loads stay in flight across the barrier
#define WAITBAR(N)                                        \
  do {                                                    \
    asm volatile("s_waitcnt vmcnt(" #N ")" ::: "memory"); \
    __builtin_amdgcn_sched_barrier(0);                    \
    __builtin_amdgcn_s_barrier();                         \
    __builtin_amdgcn_sched_barrier(0);                    \
  } while (0)

// plain barrier (sched-fenced)
#define BARO()                                            \
  do {                                                    \
    __builtin_amdgcn_sched_barrier(0);                    \
    __builtin_amdgcn_s_barrier();                         \
    __builtin_amdgcn_sched_barrier(0);                    \
  } while (0)

// ---------------- prep: fold LoRA into Wk/Wv, cast weights + query to bf16 --
__global__ void prep_kernel(const float* __restrict__ query,
                            const float* __restrict__ W,
                            const float* __restrict__ ka, const float* __restrict__ kb,
                            const float* __restrict__ va, const float* __restrict__ vb,
                            const float* __restrict__ ow,
                            u16* __restrict__ Wm, u16* __restrict__ Wo,
                            u16* __restrict__ Aq) {
  const int W3 = 3 * DM * DM;
  const int WO = DM * DM;
  const int AQ = MROWS * DM;
  const int total = W3 + WO + AQ;
  for (int idx = blockIdx.x * blockDim.x + threadIdx.x; idx < total;
       idx += gridDim.x * blockDim.x) {
    if (idx < W3) {
      const int n = idx >> 10, k = idx & 1023;
      float w = W[idx];
      if (n >= 2 * DM) {
        const int n2 = n - 2 * DM;
        float a = 0.f;
#pragma unroll
        for (int r = 0; r < 16; ++r) a += va[r * DM + k] * vb[r * DM + n2];
        w += LORA_S * a;
      } else if (n >= DM) {
        const int n2 = n - DM;
        float a = 0.f;
#pragma unroll
        for (int r = 0; r < 16; ++r) a += ka[r * DM + k] * kb[r * DM + n2];
        w += LORA_S * a;
      }
      Wm[idx] = f2bf(w);
    } else if (idx < W3 + WO) {
      const int i = idx - W3;
      Wo[i] = f2bf(ow[i]);
    } else {
      const int i = idx - W3 - WO;
      Aq[i] = f2bf(query[i]);
    }
  }
}

// ---------------- GEMM: C[m][n] = sum_k A[m][k]*Bt[n][k] + bias[n] ----------
// R9-winning config: BK=32, 4-buffer LDS rotation (64 KB), counted vmcnt(8):
// 3 stages in flight, never drained to 0 in the main loop. Plain 2-D grid.
// Packed LDS tiles: 64 rows x 128B, XOR-swizzled.
// EPIL 0: scatter q/k + V via LDS-transpose (coalesced 16B). EPIL 1: fp32 C.
template <int EPIL>
__global__ __launch_bounds__(256) void gemm_bt(
    const u16* __restrict__ A, const u16* __restrict__ Bt,
    const float* __restrict__ bias, float* __restrict__ Cf,
    u16* __restrict__ Qb, u16* __restrict__ Kb, u16* __restrict__ Vt,
    int M, int N, int K) {
  constexpr int BM = 128, BN = 128, BK = 32;
  __shared__ alignas(16) u16 SM[4][2][4096];  // 64 KB: [buf][A/B][64x64 u16]
  const int tid = threadIdx.x;
  const int wv = tid >> 6, ln = tid & 63;
  const int l16 = ln & 15, lhi = ln >> 4;
  const int row0 = blockIdx.x * BM, col0 = blockIdx.y * BN;
  const int wr = (wv >> 1) * 64, wc = (wv & 1) * 64;

  f32x4 acc[4][4];
#pragma unroll
  for (int i = 0; i < 4; ++i)
#pragma unroll
    for (int j2 = 0; j2 < 4; ++j2) acc[i][j2] = f32x4{0.f, 0.f, 0.f, 0.f};

  // staging lane map: instr j in {0,1}: ldsrow = wv*16 + j*8 + (ln>>3), s=ln&7
  // inverse swizzle: l = s ^ (ldsrow&7); logical r = ldsrow + 64*(l>>2),
  // c = (l&3)*8  -> linear dest + pre-swizzled source (m201/G21 pattern)
  const int lrA = wv * 16 + (ln >> 3);   // j=0 ldsrow
  const int lrB = lrA + 8;               // j=1 ldsrow
  const int s_ = ln & 7;
  const int la = s_ ^ (lrA & 7), lb = s_ ^ (lrB & 7);
  const int ra = lrA + 64 * (la >> 2), ca = (la & 3) * 8;
  const int rb = lrB + 64 * (lb >> 2), cb = (lb & 3) * 8;

  const u16* pa0 = A + (size_t)(row0 + ra) * K + ca;
  const u16* pa1 = A + (size_t)(row0 + rb) * K + cb;
  const u16* pb0 = Bt + (size_t)(col0 + ra) * K + ca;
  const u16* pb1 = Bt + (size_t)(col0 + rb) * K + cb;

  auto stagep = [&](int buf) {
    gload_lds16(pa0, &SM[buf][0][(wv * 16) * 64]);
    gload_lds16(pa1, &SM[buf][0][(wv * 16 + 8) * 64]);
    gload_lds16(pb0, &SM[buf][1][(wv * 16) * 64]);
    gload_lds16(pb1, &SM[buf][1][(wv * 16 + 8) * 64]);
    pa0 += BK; pa1 += BK; pb0 += BK; pb1 += BK;
  };

  auto compute = [&](int buf) {
    const u16* Al = SM[buf][0];
    const u16* Bl = SM[buf][1];
    bf16x8 af[4], bfr[4];
#pragma unroll
    for (int m = 0; m < 4; ++m) {
      const int r = wr + m * 16 + l16, lr = r & 63;
      const int sl = (lhi | ((r >> 6) << 2)) ^ (lr & 7);
      af[m] = *(const bf16x8*)&Al[lr * 64 + sl * 8];
    }
#pragma unroll
    for (int n = 0; n < 4; ++n) {
      const int r = wc + n * 16 + l16, lr = r & 63;
      const int sl = (lhi | ((r >> 6) << 2)) ^ (lr & 7);
      bfr[n] = *(const bf16x8*)&Bl[lr * 64 + sl * 8];
    }
#pragma unroll
    for (int m = 0; m < 4; ++m)
#pragma unroll
      for (int n = 0; n < 4; ++n) acc[m][n] = mfma16(af[m], bfr[n], acc[m][n]);
  };

  const int NS = K / BK;  // 32 for K=1024
  stagep(0); stagep(1); stagep(2);  // 12 loads/wave in flight

  for (int t4 = 0; t4 < NS - 4; t4 += 4) {
    WAITBAR(8); compute(0); stagep(3);
    WAITBAR(8); compute(1); stagep(0);
    WAITBAR(8); compute(2); stagep(1);
    WAITBAR(8); compute(3); stagep(2);
  }
  WAITBAR(8); compute(0); stagep(3);
  WAITBAR(8); compute(1);
  WAITBAR(4); compute(2);
  WAITBAR(0); compute(3);

  if constexpr (EPIL == 0) {
    if (col0 >= 2 * DM) {
      // ---- V block: transpose 128x128 tile through LDS, coalesced stores
      u16* Cl = (u16*)SM;  // first 32 KB; all buffers dead past final barrier
      __syncthreads();
#pragma unroll
      for (int m = 0; m < 4; ++m)
#pragma unroll
        for (int n = 0; n < 4; ++n) {
          const int lc = wc + n * 16 + l16;
          const float bc = bias[col0 + lc];
#pragma unroll
          for (int r = 0; r < 4; ++r) {
            const int rl = wr + m * 16 + lhi * 4 + r;
            const int tl = rl >> 1, bb = rl & 1;
            Cl[lc * 128 + bb * 64 + (((tl >> 3) ^ (lc & 7)) << 3) + (tl & 7)] =
                f2bf(acc[m][n][r] + bc);
          }
        }
      __syncthreads();
      const int h0 = (col0 - 2 * DM) >> 6;
      const int t0 = row0 >> 1;
#pragma unroll
      for (int i = 0; i < 8; ++i) {
        const int cid = i * 256 + tid;  // 2048 chunks of 8 u16
        const int lc = cid >> 4, bb = (cid >> 3) & 1, tc = cid & 7;
        bf16x8 ch = *(const bf16x8*)&Cl[lc * 128 + bb * 64 + ((tc ^ (lc & 7)) << 3)];
        const int h = h0 + (lc >> 6), dd = lc & 63;
        *(bf16x8*)&Vt[(((size_t)(bb * NH + h)) * HD + dd) * T_LEN + t0 + tc * 8] = ch;
      }
      return;
    }
  }

#pragma unroll
  for (int m = 0; m < 4; ++m) {
#pragma unroll
    for (int n = 0; n < 4; ++n) {
      const int col = col0 + wc + n * 16 + l16;
      const float bc = bias[col];
#pragma unroll
      for (int r = 0; r < 4; ++r) {
        const int row = row0 + wr + m * 16 + lhi * 4 + r;
        const float v = acc[m][n][r] + bc;
        if constexpr (EPIL == 0) {
          const int t = row >> 1, b = row & 1;  // row = t*BSZ + b
          if (col < DM) {
            const int h = col >> 6, dd = col & 63;
            Qb[(((size_t)(b * NH + h)) * T_LEN + t) * HD + dd] = f2bf(v * QSCALE);
          } else {
            const int c2 = col - DM, h = c2 >> 6, dd = c2 & 63;
            Kb[(((size_t)(b * NH + h)) * T_LEN + t) * HD + dd] = f2bf(v);
          }
        } else {
          Cf[(size_t)row * N + col] = v;
        }
      }
    }
  }
}

// ---------------- flash attention: swapped-QK^T, max-free in-reg softmax ----
// 4 waves x 32 q-rows; 32x32x16 MFMA; KV tiles of 64 in a 4-buffer rotation.
// TWO tiles per barrier phase; counted vmcnt(8) keeps 16 loads/wave in flight.
// T5: setprio(1) around the MFMA clusters (phase-split makes it effective).
__global__ __launch_bounds__(256) void attn_kernel(const u16* __restrict__ Qb,
                                                   const u16* __restrict__ Kb,
                                                   const u16* __restrict__ Vt,
                                                   u16* __restrict__ Ob) {
  constexpr int KBLK = 64;
  __shared__ alignas(16) u16 KV[4][2][32 * 128];  // 64 KB: [buf][K/V][packed tile]

  const int tid = threadIdx.x;
  const int wv = tid >> 6, ln = tid & 63;
  const int l32 = ln & 31, hi = ln >> 5;

  // XCD-aware bijective swizzle (T1): each XCD gets 4 consecutive heads
  const int bid = blockIdx.x;
  const int lb = (bid & 7) * 64 + (bid >> 3);
  const int bh = lb >> 4;                 // head index 0..31
  const int b = bh >> 4, h = bh & 15;
  const int q0 = (lb & 15) * 128 + wv * 32;

  const u16* Qh = Qb + (size_t)bh * T_LEN * HD;
  const u16* Kh = Kb + (size_t)bh * T_LEN * HD;
  const u16* Vh = Vt + (size_t)bh * HD * T_LEN;

  // Q B-fragments: row = q = l32, k = kd*16 + hi*8 + j  (pre-scaled by QSCALE)
  bf16x8 qf[4];
#pragma unroll
  for (int kd = 0; kd < 4; ++kd)
    qf[kd] = *(const bf16x8*)&Qh[(size_t)(q0 + l32) * HD + kd * 16 + hi * 8];

  bf16x8 ones;
#pragma unroll
  for (int i = 0; i < 8; ++i) ones[i] = (short)0x3F80;  // bf16 1.0

  f32x16 ot[2] = {f32x16{}, f32x16{}};  // O^T accumulators (dim tiles 0,1)
  f32x16 lacc = f32x16{};               // row-sum accumulator (all rows = li)

  // staging lane map (inverse swizzle), hoisted once; running global pointers
  const int g_row = ln >> 4;            // 0..3 within instr
  const int g_s   = ln & 15;
  const int j0 = wv * 2, j1 = wv * 2 + 1;
  const int row0r = 4 * j0 + g_row, row1r = 4 * j1 + g_row;
  const int l0 = g_s ^ (row0r & 15), l1 = g_s ^ (row1r & 15);
  const int lr0 = row0r + 32 * (l0 >> 3), lr1 = row1r + 32 * (l1 >> 3);
  const int c80 = (l0 & 7) * 8, c81 = (l1 & 7) * 8;

  const u16* ks0 = Kh + (size_t)lr0 * HD + c80;
  const u16* ks1 = Kh + (size_t)lr1 * HD + c81;
  const u16* vs0 = Vh + (size_t)lr0 * T_LEN + c80;
  const u16* vs1 = Vh + (size_t)lr1 * T_LEN + c81;

  auto stagep = [&](int buf) {
    gload_lds16(ks0, &KV[buf][0][j0 * 512]);
    gload_lds16(ks1, &KV[buf][0][j1 * 512]);
    gload_lds16(vs0, &KV[buf][1][j0 * 512]);
    gload_lds16(vs1, &KV[buf][1][j1 * 512]);
    ks0 += KBLK * HD; ks1 += KBLK * HD; vs0 += KBLK; vs1 += KBLK;
  };

  auto compute = [&](int buf) {
    const u16* Kl = KV[buf][0];
    const u16* Vl = KV[buf][1];
    // S^T[key][q]: st[mk], key = mk*32 + (r&3) + 8*(r>>2) + 4*hi, q col = l32
    f32x16 st[2] = {f32x16{}, f32x16{}};
    __builtin_amdgcn_s_setprio(1);
#pragma unroll
    for (int kd = 0; kd < 4; ++kd) {
      bf16x8 k0 = *(const bf16x8*)&Kl[kvswz(l32, kd * 2 + hi)];
      bf16x8 k1 = *(const bf16x8*)&Kl[kvswz(l32, 8 + kd * 2 + hi)];
      st[0] = mfma32(k0, qf[kd], st[0]);
      st[1] = mfma32(k1, qf[kd], st[1]);
    }
    __builtin_amdgcn_s_setprio(0);
    // P = exp2(S^T) packed to bf16 pairs (truncation; bias cancels in P/l)
    uint32_t c[2][8];
#pragma unroll
    for (int mk = 0; mk < 2; ++mk)
#pragma unroll
      for (int d = 0; d < 8; ++d)
        c[mk][d] = __builtin_amdgcn_perm(e2r(st[mk][2 * d + 1]),
                                         e2r(st[mk][2 * d]), 0x07060302u);
    // O^T += V^T P^T ; lacc += 1^T P^T (row sum via matrix pipe)
    __builtin_amdgcn_s_setprio(1);
#pragma unroll
    for (int ksl = 0; ksl < 4; ++ksl) {
      const int mk = ksl >> 1, s2 = ksl & 1;
      uint32_t a0 = c[mk][4 * s2 + 0], b0 = c[mk][4 * s2 + 2];
      uint32_t a1 = c[mk][4 * s2 + 1], b1 = c[mk][4 * s2 + 3];
      u32x2 r0 = __builtin_amdgcn_permlane32_swap(a0, b0, false, false);
      u32x2 r1 = __builtin_amdgcn_permlane32_swap(a1, b1, false, false);
      union { bf16x8 v; uint32_t u[4]; } pu;
      pu.u[0] = r0[0]; pu.u[1] = r1[0]; pu.u[2] = r0[1]; pu.u[3] = r1[1];
      bf16x8 vf0 = *(const bf16x8*)&Vl[kvswz(l32, ksl * 2 + hi)];
      bf16x8 vf1 = *(const bf16x8*)&Vl[kvswz(l32, 8 + ksl * 2 + hi)];
      ot[0] = mfma32(vf0, pu.v, ot[0]);
      ot[1] = mfma32(vf1, pu.v, ot[1]);
      lacc = mfma32(ones, pu.v, lacc);
    }
    __builtin_amdgcn_s_setprio(0);
  };

  // prologue: 4 tiles (16 loads/wave) in flight
  stagep(0); stagep(1); stagep(2); stagep(3);

  // 2 tiles per phase; 7 iterations cover tiles 0..27, staging 4..31.
  // WAITBAR(8): own 8 oldest loads (= 2 oldest tiles) complete for all waves.
  for (int it7 = 0; it7 < 7; ++it7) {
    WAITBAR(8); compute(0); compute(1); BARO(); stagep(0); stagep(1);
    WAITBAR(8); compute(2); compute(3); BARO(); stagep(2); stagep(3);
  }
  // tail: tiles 28..31
  WAITBAR(8); compute(0); compute(1);
  WAITBAR(0); compute(2); compute(3);

  // epilogue: O^T[dim][q]/li -> Ob[(t*BSZ+b)*DM + h*64 + dim], 4-dim packed
  const float inv = 1.0f / lacc[0];
  const size_t rowbase = ((size_t)(q0 + l32) * BSZ + b) * DM + h * HD;
#pragma unroll
  for (int dt = 0; dt < 2; ++dt) {
#pragma unroll
    for (int g = 0; g < 4; ++g) {
      const float v0 = ot[dt][4 * g + 0] * inv;
      const float v1 = ot[dt][4 * g + 1] * inv;
      const float v2 = ot[dt][4 * g + 2] * inv;
      const float v3 = ot[dt][4 * g + 3] * inv;
      u32x2 w; w[0] = pk2bf(v0, v1); w[1] = pk2bf(v2, v3);
      const int dim = dt * 32 + 8 * g + 4 * hi;
      *(u32x2*)&Ob[rowbase + dim] = w;
    }
  }
}

// ---------------- launcher --------------------------------------------------
extern "C" void kernel_launch(void* const* d_in, const int* in_sizes, int n_in,
                              void* d_out, int out_size, void* d_ws, size_t ws_size,
                              hipStream_t stream) {
  const float* query = (const float*)d_in[0];
  const float* W     = (const float*)d_in[5];
  const float* bias  = (const float*)d_in[6];
  const float* ow    = (const float*)d_in[7];
  const float* ob    = (const float*)d_in[8];
  const float* ka    = (const float*)d_in[9];
  const float* kb    = (const float*)d_in[10];
  const float* va    = (const float*)d_in[11];
  const float* vb    = (const float*)d_in[12];

  char* ws = (char*)d_ws;
  u16* Wm = (u16*)ws; ws += (size_t)3 * DM * DM * 2;       // 6 MB
  u16* Wo = (u16*)ws; ws += (size_t)DM * DM * 2;           // 2 MB
  u16* Aq = (u16*)ws; ws += (size_t)MROWS * DM * 2;        // 8 MB
  u16* Qb = (u16*)ws; ws += (size_t)BSZ * NH * T_LEN * HD * 2;  // 8 MB
  u16* Kb = (u16*)ws; ws += (size_t)BSZ * NH * T_LEN * HD * 2;  // 8 MB
  u16* Vt = (u16*)ws; ws += (size_t)BSZ * NH * T_LEN * HD * 2;  // 8 MB
  u16* Ob = (u16*)ws; ws += (size_t)MROWS * DM * 2;        // 8 MB

  prep_kernel<<<2048, 256, 0, stream>>>(query, W, ka, kb, va, vb, ow, Wm, Wo, Aq);

  gemm_bt<0><<<dim3(MROWS / 128, (3 * DM) / 128), 256, 0, stream>>>(
      Aq, Wm, bias, nullptr, Qb, Kb, Vt, MROWS, 3 * DM, DM);

  attn_kernel<<<512, 256, 0, stream>>>(Qb, Kb, Vt, Ob);

  gemm_bt<1><<<dim3(MROWS / 128, DM / 128), 256, 0, stream>>>(
      Ob, Wo, ob, (float*)d_out, nullptr, nullptr, nullptr, MROWS, DM, DM);
}